// Round 1
// 2977.314 us; speedup vs baseline: 1.3931x; 1.3931x over previous
//
#include <hip/hip_runtime.h>
#include <hip/hip_cooperative_groups.h>

namespace cg = cooperative_groups;

// Problem constants
#define VSZ   32000
#define HSZ   512
#define LSZ   4
#define BSZ   32
#define TSZ   51            // MAX_LEN + 1
#define OUT_LOGITS 52224000 // B*T*V
#define MPAD  1664          // T*B=1632 padded to 26*64

// ws layout (float offsets)
// XH: ping-pong x|h state, [2][L][K/4=256][32 b][4] floats (k<512 = x, k>=512 = h)
#define WS_XH    0          // 262144 floats
#define WS_HTOP  262144     // bf16 [1664][512] = 851968 ushorts = 425984 float-slots
#define WS_WB    688128     // bf16 [32000][512]

typedef __attribute__((ext_vector_type(8))) short bf16x8;
typedef __attribute__((ext_vector_type(4))) float f32x4;

static __device__ __forceinline__ unsigned short f2bf(float f) {
    unsigned int u = __float_as_uint(f);
    unsigned int r = (u + 0x7FFFu + ((u >> 16) & 1u)) >> 16;   // RNE
    return (unsigned short)r;
}

// ---------------- Kernel C: W_out fp32 -> bf16 ----------------
__global__ __launch_bounds__(256) void convw_kernel(const float* __restrict__ W,
                                                    unsigned short* __restrict__ WB) {
    const int n4 = VSZ * HSZ / 4;  // 4,096,000 float4s
    for (int i = blockIdx.x * 256 + threadIdx.x; i < n4; i += gridDim.x * 256) {
        float4 f = ((const float4*)W)[i];
        ushort4 o;
        o.x = f2bf(f.x); o.y = f2bf(f.y); o.z = f2bf(f.z); o.w = f2bf(f.w);
        ((ushort4*)WB)[i] = o;
    }
}

// ---------------- Kernel A: wavefront-pipelined cooperative LSTM ----------------
// 256 blocks x 512 threads. Block = (layer l = blockIdx>>6, j-tile jt = blockIdx&63).
// Stage s: layer l computes timestep t = s - l (valid 0..50); 54 stages total.
// Thread: b = tid&31, kh = (tid>>5)&1 (x-half vs h-half of K), jl = tid>>6 (wave id).
// NEW vs prev version:
//  - The block's 64 weight rows (128 KiB fp32, constant over all stages) are
//    preloaded ONCE into dynamic LDS; inner-loop weight reads are LDS broadcasts
//    (32 lanes same addr; 2 unique addrs/instr = free 2-way). Kills the per-stage
//    4 MB/XCD L2-thrash + HBM re-fetch (FETCH_SIZE was 880 MB).
//  - XH state packed [k/4][b][4] so the per-lane x operand is ONE dwordx4
//    (512 B contiguous per half-wave) instead of 4 scalar loads.
__global__ __launch_bounds__(512) void lstm_kernel(
    const float* __restrict__ dec_h, const float* __restrict__ dec_c,
    const int* __restrict__ target, const float* __restrict__ emb,
    const float* __restrict__ Wih, const float* __restrict__ Whh,
    const float* __restrict__ bih, const float* __restrict__ bhh,
    float* __restrict__ ws, float* __restrict__ out)
{
    extern __shared__ float Wlds[];   // [8 jl][4 g][2 kh][512] = 131072 B
    cg::grid_group grid = cg::this_grid();

    float* XH = ws + WS_XH;                       // [2][4][256][32][4]
    unsigned short* HTOP = (unsigned short*)(ws + WS_HTOP);

    const int tid = threadIdx.x;
    const int b   = tid & 31;
    const int kh  = (tid >> 5) & 1;
    const int jl  = tid >> 6;            // 0..7 == wave index
    const int l   = blockIdx.x >> 6;     // 0..3
    const int jt  = blockIdx.x & 63;     // 0..63
    const int j   = jt * 8 + jl;         // 0..511

    // per-thread fused biases (constant across stages)
    const int rj = l * 2048 + j;
    const float bias0 = bih[rj]          + bhh[rj];
    const float bias1 = bih[rj + 512]    + bhh[rj + 512];
    const float bias2 = bih[rj + 1024]   + bhh[rj + 1024];
    const float bias3 = bih[rj + 1536]   + bhh[rj + 1536];

    // cell state lives in a register (this thread exclusively owns (l, b, j))
    float c_reg = dec_c[(l * 32 + b) * 512 + j];

    // ---- one-time: preload this block's 64 weight rows into LDS ----
    // row id = (jl2, g, khh); 8 threads per row, 16 float4 each (128 f4/row)
    {
        const int rowid = tid >> 3;          // 0..63
        const int lane8 = tid & 7;
        const int jl2 = rowid >> 3;          // 0..7
        const int g   = (rowid >> 1) & 3;    // 0..3
        const int khh = rowid & 1;           // 0: W_ih, 1: W_hh
        const float* W = khh ? Whh : Wih;
        const float4* s4 = (const float4*)(W + (size_t)(l * 2048 + g * 512 + jt * 8 + jl2) * 512);
        float4* d4 = (float4*)(Wlds + jl2 * 4096 + g * 1024 + khh * 512);
        #pragma unroll
        for (int i = 0; i < 16; ++i)
            d4[lane8 + i * 8] = s4[lane8 + i * 8];
    }

    // ---- init: XH[1][0][x] = emb[SOS], XH[(l+1)&1][l][h] = dec_h ----
    {
        const int gid = blockIdx.x * 512 + tid;   // 0..131071
        if (gid < 16384) {
            int k = gid >> 5, bb = gid & 31;
            XH[131072 + (k >> 2) * 128 + bb * 4 + (k & 3)] = emb[k];  // SOS == 0
        }
        if (gid < 65536) {
            int l2 = gid >> 14;
            int rem = gid & 16383;
            int j2 = rem >> 5, b2 = rem & 31;
            XH[((l2 + 1) & 1) * 131072 + l2 * 32768 +
               (128 + (j2 >> 2)) * 128 + b2 * 4 + (j2 & 3)] =
                dec_h[(l2 * 32 + b2) * 512 + j2];
        }
    }
    grid.sync();   // also covers the LDS preload (block-level barrier included)

    // this thread's LDS weight base: 4 gate rows at +g*256 float4s
    const float4* wp4 = (const float4*)Wlds + jl * 1024 + kh * 128;

    for (int s = 0; s < 54; ++s) {
        const int pp = (s + 1) & 1;   // read parity  = (s-1)&1
        const int pw = s & 1;         // write parity
        const int t  = s - l;

        // pre-pass: build layer-0 x (embedding of token t_next = s+1) for next stage
        if (s < 50 && tid < 64) {
            int e = blockIdx.x * 64 + tid;        // 0..16383
            int k = e >> 5, bb = e & 31;
            int tok = target[bb * TSZ + s];       // token index for t = s+1
            XH[pw * 131072 + (k >> 2) * 128 + bb * 4 + (k & 3)] = emb[tok * 512 + k];
        }

        if (t >= 0 && t <= 50) {
            const float4* xp4 = (const float4*)(XH + pp * 131072 + l * 32768 + kh * 16384) + b;

            float a0 = 0.f, a1 = 0.f, a2 = 0.f, a3 = 0.f;
            #pragma unroll 8
            for (int kk = 0; kk < 128; ++kk) {
                float4 xv = xp4[kk * 32];
                float4 w0 = wp4[kk];
                float4 w1 = wp4[kk + 256];
                float4 w2 = wp4[kk + 512];
                float4 w3 = wp4[kk + 768];
                a0 += w0.x * xv.x; a0 += w0.y * xv.y; a0 += w0.z * xv.z; a0 += w0.w * xv.w;
                a1 += w1.x * xv.x; a1 += w1.y * xv.y; a1 += w1.z * xv.z; a1 += w1.w * xv.w;
                a2 += w2.x * xv.x; a2 += w2.y * xv.y; a2 += w2.z * xv.z; a2 += w2.w * xv.w;
                a3 += w3.x * xv.x; a3 += w3.y * xv.y; a3 += w3.z * xv.z; a3 += w3.w * xv.w;
            }
            // combine x-half and h-half (partner lane is lane^32, same wave)
            a0 += __shfl_xor(a0, 32);
            a1 += __shfl_xor(a1, 32);
            a2 += __shfl_xor(a2, 32);
            a3 += __shfl_xor(a3, 32);

            // LSTM cell (computed redundantly by both halves; stores are split)
            float pi = a0 + bias0, pf = a1 + bias1, pg = a2 + bias2, po = a3 + bias3;
            float ig = 1.f / (1.f + expf(-pi));
            float fg = 1.f / (1.f + expf(-pf));
            float gg = tanhf(pg);
            float og = 1.f / (1.f + expf(-po));
            float cn = fg * c_reg + ig * gg;
            float hn = og * tanhf(cn);                  // pre-clamp h
            c_reg     = fminf(fmaxf(cn, -50.f), 50.f);  // clipped carry
            float hcl = fminf(fmaxf(hn, -50.f), 50.f);  // clipped h carry

            if (kh == 0) {
                // recurrent h input for this layer at t+1 (clipped, per reference)
                XH[pw * 131072 + l * 32768 + (128 + (j >> 2)) * 128 + b * 4 + (j & 3)] = hcl;
                if (l == 3)
                    HTOP[((t * 32 + b) << 9) + j] = f2bf(hn);   // pre-clamp top h
            } else {
                if (l < 3)
                    XH[pw * 131072 + (l + 1) * 32768 + (j >> 2) * 128 + b * 4 + (j & 3)] = hn;
                if (t == 50)
                    out[OUT_LOGITS + ((l * 32 + b) << 9) + j] = hcl;     // h_fin
            }
        }
        grid.sync();
    }
}

// ---------------- Kernel B: bf16 MFMA projection (gemm_bt) ----------------
// C[m, v] = sum_k HTOP[m,k] * WB[v,k] + b_out[v];  m = t*32 + b  ->  out[(b*51+t)*V + v]
__global__ __launch_bounds__(256) void proj_kernel(
    const unsigned short* __restrict__ A, const unsigned short* __restrict__ Bm,
    const float* __restrict__ bout, float* __restrict__ out)
{
    __shared__ unsigned short As[64 * 40];
    __shared__ unsigned short Bs[64 * 40];
    const int tid = threadIdx.x;
    const int bn = blockIdx.x;   // 0..499
    const int bm = blockIdx.y;   // 0..25
    const int w = tid >> 6, lane = tid & 63;
    const int lr = lane & 15, lq = lane >> 4;

    f32x4 acc0 = {0.f, 0.f, 0.f, 0.f};
    f32x4 acc1 = {0.f, 0.f, 0.f, 0.f};
    f32x4 acc2 = {0.f, 0.f, 0.f, 0.f};
    f32x4 acc3 = {0.f, 0.f, 0.f, 0.f};

    const int r = tid >> 2, c8 = (tid & 3) * 8;
    const unsigned short* Ag = A + (bm * 64 + r) * HSZ + c8;
    const unsigned short* Bg = Bm + (size_t)(bn * 64 + r) * HSZ + c8;

    for (int kt = 0; kt < 16; ++kt) {
        *(uint4*)&As[r * 40 + c8] = *(const uint4*)(Ag + kt * 32);
        *(uint4*)&Bs[r * 40 + c8] = *(const uint4*)(Bg + kt * 32);
        __syncthreads();
        bf16x8 af = *(const bf16x8*)&As[(w * 16 + lr) * 40 + lq * 8];
        bf16x8 b0 = *(const bf16x8*)&Bs[(0 * 16 + lr) * 40 + lq * 8];
        bf16x8 b1 = *(const bf16x8*)&Bs[(1 * 16 + lr) * 40 + lq * 8];
        bf16x8 b2 = *(const bf16x8*)&Bs[(2 * 16 + lr) * 40 + lq * 8];
        bf16x8 b3 = *(const bf16x8*)&Bs[(3 * 16 + lr) * 40 + lq * 8];
        acc0 = __builtin_amdgcn_mfma_f32_16x16x32_bf16(af, b0, acc0, 0, 0, 0);
        acc1 = __builtin_amdgcn_mfma_f32_16x16x32_bf16(af, b1, acc1, 0, 0, 0);
        acc2 = __builtin_amdgcn_mfma_f32_16x16x32_bf16(af, b2, acc2, 0, 0, 0);
        acc3 = __builtin_amdgcn_mfma_f32_16x16x32_bf16(af, b3, acc3, 0, 0, 0);
        __syncthreads();
    }

    f32x4 accs[4] = {acc0, acc1, acc2, acc3};
    #pragma unroll
    for (int nt = 0; nt < 4; ++nt) {
        const int v = bn * 64 + nt * 16 + lr;
        const float bo = bout[v];
        #pragma unroll
        for (int reg = 0; reg < 4; ++reg) {
            const int m = bm * 64 + w * 16 + lq * 4 + reg;
            if (m < TSZ * BSZ) {
                const int tt = m >> 5, bb = m & 31;
                out[(size_t)(bb * TSZ + tt) * VSZ + v] = accs[nt][reg] + bo;
            }
        }
    }
}

extern "C" void kernel_launch(void* const* d_in, const int* in_sizes, int n_in,
                              void* d_out, int out_size, void* d_ws, size_t ws_size,
                              hipStream_t stream) {
    const float* dec_h = (const float*)d_in[1];
    const float* dec_c = (const float*)d_in[2];
    const int*   tgt   = (const int*)d_in[3];
    const float* emb   = (const float*)d_in[4];
    const float* Wih   = (const float*)d_in[5];
    const float* Whh   = (const float*)d_in[6];
    const float* bihp  = (const float*)d_in[7];
    const float* bhhp  = (const float*)d_in[8];
    const float* Wout  = (const float*)d_in[9];
    const float* bout  = (const float*)d_in[10];
    float* out = (float*)d_out;
    float* ws  = (float*)d_ws;

    unsigned short* HTOP = (unsigned short*)(ws + WS_HTOP);
    unsigned short* WB   = (unsigned short*)(ws + WS_WB);

    // opt-in to 128 KiB dynamic LDS for the LSTM kernel (host-side, once)
    static bool s_attr_done = false;
    if (!s_attr_done) {
        (void)hipFuncSetAttribute(reinterpret_cast<const void*>(lstm_kernel),
                                  hipFuncAttributeMaxDynamicSharedMemorySize,
                                  131072);
        s_attr_done = true;
    }

    // W_out -> bf16 (independent of the recurrence)
    convw_kernel<<<4096, 256, 0, stream>>>(Wout, WB);

    // wavefront-pipelined cooperative LSTM (54 stages), 128 KiB LDS weights
    void* args[] = { (void*)&dec_h, (void*)&dec_c, (void*)&tgt, (void*)&emb,
                     (void*)&Wih, (void*)&Whh, (void*)&bihp, (void*)&bhhp,
                     (void*)&ws, (void*)&out };
    hipLaunchCooperativeKernel(reinterpret_cast<void*>(lstm_kernel),
                               dim3(256), dim3(512), args, 131072, stream);

    // batched output projection
    proj_kernel<<<dim3(VSZ / 64, MPAD / 64), 256, 0, stream>>>(HTOP, WB, bout, out);
}

// Round 2
// 1888.625 us; speedup vs baseline: 2.1961x; 1.5764x over previous
//
#include <hip/hip_runtime.h>

// Problem constants
#define VSZ   32000
#define HSZ   512
#define LSZ   4
#define BSZ   32
#define TSZ   51            // MAX_LEN + 1
#define OUT_LOGITS 52224000 // B*T*V
#define MPAD  1664          // T*B=1632 padded to 26*64

// ws layout (float offsets)
// XH: ping-pong x|h state, [2][L][K/4=256][32 b][4] floats (k<512 = x, k>=512 = h)
#define WS_XH    0          // 262144 floats
#define WS_HTOP  262144     // bf16 [1664][512] = 851968 ushorts = 425984 float-slots
#define WS_WB    688128     // bf16 [32000][512] = 8192000 float-slots
#define WS_CNT   8880128    // u32 counters: [4][64] stage counters + [256] init

typedef __attribute__((ext_vector_type(8))) short bf16x8;
typedef __attribute__((ext_vector_type(4))) float f32x4;

static __device__ __forceinline__ unsigned short f2bf(float f) {
    unsigned int u = __float_as_uint(f);
    unsigned int r = (u + 0x7FFFu + ((u >> 16) & 1u)) >> 16;   // RNE
    return (unsigned short)r;
}

// agent-scope (device-coherent) state store: write-through past the per-XCD L2,
// so cross-XCD readers see it after a plain acquire-fence, and nothing is left
// dirty for the release fence to write back.
static __device__ __forceinline__ void st_xh(float* p, float v) {
    __hip_atomic_store(p, v, __ATOMIC_RELAXED, __HIP_MEMORY_SCOPE_AGENT);
}
static __device__ __forceinline__ unsigned int ld_cnt(unsigned int* p) {
    return __hip_atomic_load(p, __ATOMIC_RELAXED, __HIP_MEMORY_SCOPE_AGENT);
}

// ---------------- Kernel C: W_out fp32 -> bf16 ----------------
__global__ __launch_bounds__(256) void convw_kernel(const float* __restrict__ W,
                                                    unsigned short* __restrict__ WB) {
    const int n4 = VSZ * HSZ / 4;  // 4,096,000 float4s
    for (int i = blockIdx.x * 256 + threadIdx.x; i < n4; i += gridDim.x * 256) {
        float4 f = ((const float4*)W)[i];
        ushort4 o;
        o.x = f2bf(f.x); o.y = f2bf(f.y); o.z = f2bf(f.z); o.w = f2bf(f.w);
        ((ushort4*)WB)[i] = o;
    }
}

// ---------------- Kernel A: point-to-point pipelined LSTM ----------------
// 256 blocks x 512 threads, cooperative launch for co-residency ONLY (no grid.sync).
// Block = (layer l = blockIdx>>6, j-tile jt = blockIdx&63). Stage s: layer l
// computes t = s - l. Per-stage sync is point-to-point: block (l,jt) waits for
//   cnt[l][s-1]==64   (own layer's h(t-1) + layer-0 emb prefill; also WAR cover)
//   cnt[l-1][s-1]==64 (x producer)
//   cnt[l+1][s-1]==64 (WAR: our x-writes into region [l+1] reuse the parity
//                      buffer layer l+1 read at stage s-1)
// then acquire-fence (per-CU/XCD cache inv), computes, release-fence + arrive.
// State stores are agent-scope write-through; x loads are plain cached float4
// (the 8x intra-block read reuse stays in L1/L2 after the one inv per stage).
__global__ __launch_bounds__(512) void lstm_kernel(
    const float* __restrict__ dec_h, const float* __restrict__ dec_c,
    const int* __restrict__ target, const float* __restrict__ emb,
    const float* __restrict__ Wih, const float* __restrict__ Whh,
    const float* __restrict__ bih, const float* __restrict__ bhh,
    float* __restrict__ ws, float* __restrict__ out)
{
    extern __shared__ float Wlds[];   // [8 jl][4 g][2 kh][512] = 131072 B

    float* XH = ws + WS_XH;                       // [2][4][256][32][4]
    unsigned short* HTOP = (unsigned short*)(ws + WS_HTOP);
    unsigned int* cnt = (unsigned int*)(ws + WS_CNT);   // [4][64] + [256]=init

    const int tid = threadIdx.x;
    const int b   = tid & 31;
    const int kh  = (tid >> 5) & 1;
    const int jl  = tid >> 6;            // 0..7 == wave index
    const int l   = blockIdx.x >> 6;     // 0..3
    const int jt  = blockIdx.x & 63;     // 0..63
    const int j   = jt * 8 + jl;         // 0..511

    // per-thread fused biases (constant across stages)
    const int rj = l * 2048 + j;
    const float bias0 = bih[rj]          + bhh[rj];
    const float bias1 = bih[rj + 512]    + bhh[rj + 512];
    const float bias2 = bih[rj + 1024]   + bhh[rj + 1024];
    const float bias3 = bih[rj + 1536]   + bhh[rj + 1536];

    // cell state lives in a register (this thread exclusively owns (l, b, j))
    float c_reg = dec_c[(l * 32 + b) * 512 + j];

    // ---- one-time: preload this block's 64 weight rows into LDS ----
    {
        const int rowid = tid >> 3;          // 0..63
        const int lane8 = tid & 7;
        const int jl2 = rowid >> 3;          // 0..7
        const int g   = (rowid >> 1) & 3;    // 0..3
        const int khh = rowid & 1;           // 0: W_ih, 1: W_hh
        const float* W = khh ? Whh : Wih;
        const float4* s4 = (const float4*)(W + (size_t)(l * 2048 + g * 512 + jt * 8 + jl2) * 512);
        float4* d4 = (float4*)(Wlds + jl2 * 4096 + g * 1024 + khh * 512);
        #pragma unroll
        for (int i = 0; i < 16; ++i)
            d4[lane8 + i * 8] = s4[lane8 + i * 8];
    }

    // ---- init: XH[1][0][x] = emb[SOS], XH[(l+1)&1][l][h] = dec_h ----
    {
        const int gid = blockIdx.x * 512 + tid;   // 0..131071
        if (gid < 16384) {
            int k = gid >> 5, bb = gid & 31;
            st_xh(&XH[131072 + (k >> 2) * 128 + bb * 4 + (k & 3)], emb[k]);  // SOS == 0
        }
        if (gid < 65536) {
            int l2 = gid >> 14;
            int rem = gid & 16383;
            int j2 = rem >> 5, b2 = rem & 31;
            st_xh(&XH[((l2 + 1) & 1) * 131072 + l2 * 32768 +
                      (128 + (j2 >> 2)) * 128 + b2 * 4 + (j2 & 3)],
                  dec_h[(l2 * 32 + b2) * 512 + j2]);
        }
    }
    // init barrier (also covers the LDS weight preload)
    __syncthreads();
    if (tid == 0) {
        __builtin_amdgcn_fence(__ATOMIC_RELEASE, "agent");
        __hip_atomic_fetch_add(&cnt[256], 1u, __ATOMIC_RELAXED, __HIP_MEMORY_SCOPE_AGENT);
        while (ld_cnt(&cnt[256]) < 256u) { __builtin_amdgcn_s_sleep(1); }
        __builtin_amdgcn_fence(__ATOMIC_ACQUIRE, "agent");
    }
    __syncthreads();

    // this thread's LDS weight base: 4 gate rows at +g*256 float4s
    const float4* wp4 = (const float4*)Wlds + jl * 1024 + kh * 128;

    for (int s = 0; s < 54; ++s) {
        const int pp = (s + 1) & 1;   // read parity  = (s-1)&1
        const int pw = s & 1;         // write parity
        const int t  = s - l;

        // ---- WAIT: point-to-point dependency check (tid0 spins, block follows)
        if (s > 0 && tid == 0) {
            while (ld_cnt(&cnt[l * 64 + s - 1]) < 64u) {}
            if (l > 0) while (ld_cnt(&cnt[(l - 1) * 64 + s - 1]) < 64u) {}
            if (l < 3) while (ld_cnt(&cnt[(l + 1) * 64 + s - 1]) < 64u) {}
            __builtin_amdgcn_fence(__ATOMIC_ACQUIRE, "agent");
        }
        __syncthreads();

        // pre-pass: layer-0 blocks build layer-0 x (token t_next = s+1) for next stage
        if (l == 0 && s < 50 && tid < 256) {
            int e = jt * 256 + tid;               // 0..16383 across the 64 l==0 blocks
            int k = e >> 5, bb = e & 31;
            int tok = target[bb * TSZ + s];       // token index for t = s+1
            st_xh(&XH[pw * 131072 + (k >> 2) * 128 + bb * 4 + (k & 3)],
                  emb[tok * 512 + k]);
        }

        if (t >= 0 && t <= 50) {
            const float4* xp4 = (const float4*)(XH + pp * 131072 + l * 32768 + kh * 16384) + b;

            float a0 = 0.f, a1 = 0.f, a2 = 0.f, a3 = 0.f;
            #pragma unroll 8
            for (int kk = 0; kk < 128; ++kk) {
                float4 xv = xp4[kk * 32];
                float4 w0 = wp4[kk];
                float4 w1 = wp4[kk + 256];
                float4 w2 = wp4[kk + 512];
                float4 w3 = wp4[kk + 768];
                a0 += w0.x * xv.x; a0 += w0.y * xv.y; a0 += w0.z * xv.z; a0 += w0.w * xv.w;
                a1 += w1.x * xv.x; a1 += w1.y * xv.y; a1 += w1.z * xv.z; a1 += w1.w * xv.w;
                a2 += w2.x * xv.x; a2 += w2.y * xv.y; a2 += w2.z * xv.z; a2 += w2.w * xv.w;
                a3 += w3.x * xv.x; a3 += w3.y * xv.y; a3 += w3.z * xv.z; a3 += w3.w * xv.w;
            }
            // combine x-half and h-half (partner lane is lane^32, same wave)
            a0 += __shfl_xor(a0, 32);
            a1 += __shfl_xor(a1, 32);
            a2 += __shfl_xor(a2, 32);
            a3 += __shfl_xor(a3, 32);

            // LSTM cell (computed redundantly by both halves; stores are split)
            float pi = a0 + bias0, pf = a1 + bias1, pg = a2 + bias2, po = a3 + bias3;
            float ig = 1.f / (1.f + expf(-pi));
            float fg = 1.f / (1.f + expf(-pf));
            float gg = tanhf(pg);
            float og = 1.f / (1.f + expf(-po));
            float cn = fg * c_reg + ig * gg;
            float hn = og * tanhf(cn);                  // pre-clamp h
            c_reg     = fminf(fmaxf(cn, -50.f), 50.f);  // clipped carry
            float hcl = fminf(fmaxf(hn, -50.f), 50.f);  // clipped h carry

            if (kh == 0) {
                // recurrent h input for this layer at t+1 (clipped, per reference)
                st_xh(&XH[pw * 131072 + l * 32768 + (128 + (j >> 2)) * 128 + b * 4 + (j & 3)], hcl);
                if (l == 3)
                    HTOP[((t * 32 + b) << 9) + j] = f2bf(hn);   // pre-clamp top h
            } else {
                if (l < 3)
                    st_xh(&XH[pw * 131072 + (l + 1) * 32768 + (j >> 2) * 128 + b * 4 + (j & 3)], hn);
                if (t == 50)
                    out[OUT_LOGITS + ((l * 32 + b) << 9) + j] = hcl;     // h_fin
            }
        }

        // ---- ARRIVE: all stores retired (syncthreads waits vmcnt), then bump
        __syncthreads();
        if (tid == 0) {
            __builtin_amdgcn_fence(__ATOMIC_RELEASE, "agent");
            __hip_atomic_fetch_add(&cnt[l * 64 + s], 1u, __ATOMIC_RELAXED,
                                   __HIP_MEMORY_SCOPE_AGENT);
        }
    }
}

// ---------------- Kernel B: bf16 MFMA projection (gemm_bt) ----------------
// C[m, v] = sum_k HTOP[m,k] * WB[v,k] + b_out[v];  m = t*32 + b  ->  out[(b*51+t)*V + v]
__global__ __launch_bounds__(256) void proj_kernel(
    const unsigned short* __restrict__ A, const unsigned short* __restrict__ Bm,
    const float* __restrict__ bout, float* __restrict__ out)
{
    __shared__ unsigned short As[64 * 40];
    __shared__ unsigned short Bs[64 * 40];
    const int tid = threadIdx.x;
    const int bn = blockIdx.x;   // 0..499
    const int bm = blockIdx.y;   // 0..25
    const int w = tid >> 6, lane = tid & 63;
    const int lr = lane & 15, lq = lane >> 4;

    f32x4 acc0 = {0.f, 0.f, 0.f, 0.f};
    f32x4 acc1 = {0.f, 0.f, 0.f, 0.f};
    f32x4 acc2 = {0.f, 0.f, 0.f, 0.f};
    f32x4 acc3 = {0.f, 0.f, 0.f, 0.f};

    const int r = tid >> 2, c8 = (tid & 3) * 8;
    const unsigned short* Ag = A + (bm * 64 + r) * HSZ + c8;
    const unsigned short* Bg = Bm + (size_t)(bn * 64 + r) * HSZ + c8;

    for (int kt = 0; kt < 16; ++kt) {
        *(uint4*)&As[r * 40 + c8] = *(const uint4*)(Ag + kt * 32);
        *(uint4*)&Bs[r * 40 + c8] = *(const uint4*)(Bg + kt * 32);
        __syncthreads();
        bf16x8 af = *(const bf16x8*)&As[(w * 16 + lr) * 40 + lq * 8];
        bf16x8 b0 = *(const bf16x8*)&Bs[(0 * 16 + lr) * 40 + lq * 8];
        bf16x8 b1 = *(const bf16x8*)&Bs[(1 * 16 + lr) * 40 + lq * 8];
        bf16x8 b2 = *(const bf16x8*)&Bs[(2 * 16 + lr) * 40 + lq * 8];
        bf16x8 b3 = *(const bf16x8*)&Bs[(3 * 16 + lr) * 40 + lq * 8];
        acc0 = __builtin_amdgcn_mfma_f32_16x16x32_bf16(af, b0, acc0, 0, 0, 0);
        acc1 = __builtin_amdgcn_mfma_f32_16x16x32_bf16(af, b1, acc1, 0, 0, 0);
        acc2 = __builtin_amdgcn_mfma_f32_16x16x32_bf16(af, b2, acc2, 0, 0, 0);
        acc3 = __builtin_amdgcn_mfma_f32_16x16x32_bf16(af, b3, acc3, 0, 0, 0);
        __syncthreads();
    }

    f32x4 accs[4] = {acc0, acc1, acc2, acc3};
    #pragma unroll
    for (int nt = 0; nt < 4; ++nt) {
        const int v = bn * 64 + nt * 16 + lr;
        const float bo = bout[v];
        #pragma unroll
        for (int reg = 0; reg < 4; ++reg) {
            const int m = bm * 64 + w * 16 + lq * 4 + reg;
            if (m < TSZ * BSZ) {
                const int tt = m >> 5, bb = m & 31;
                out[(size_t)(bb * TSZ + tt) * VSZ + v] = accs[nt][reg] + bo;
            }
        }
    }
}

extern "C" void kernel_launch(void* const* d_in, const int* in_sizes, int n_in,
                              void* d_out, int out_size, void* d_ws, size_t ws_size,
                              hipStream_t stream) {
    const float* dec_h = (const float*)d_in[1];
    const float* dec_c = (const float*)d_in[2];
    const int*   tgt   = (const int*)d_in[3];
    const float* emb   = (const float*)d_in[4];
    const float* Wih   = (const float*)d_in[5];
    const float* Whh   = (const float*)d_in[6];
    const float* bihp  = (const float*)d_in[7];
    const float* bhhp  = (const float*)d_in[8];
    const float* Wout  = (const float*)d_in[9];
    const float* bout  = (const float*)d_in[10];
    float* out = (float*)d_out;
    float* ws  = (float*)d_ws;

    unsigned short* HTOP = (unsigned short*)(ws + WS_HTOP);
    unsigned short* WB   = (unsigned short*)(ws + WS_WB);

    // opt-in to 128 KiB dynamic LDS for the LSTM kernel (host-side, once)
    static bool s_attr_done = false;
    if (!s_attr_done) {
        (void)hipFuncSetAttribute(reinterpret_cast<const void*>(lstm_kernel),
                                  hipFuncAttributeMaxDynamicSharedMemorySize,
                                  131072);
        s_attr_done = true;
    }

    // zero the p2p sync counters (graph-capture safe)
    hipMemsetAsync(ws + WS_CNT, 0, 1040, stream);

    // W_out -> bf16 (independent of the recurrence)
    convw_kernel<<<4096, 256, 0, stream>>>(Wout, WB);

    // point-to-point pipelined LSTM (cooperative launch for co-residency only)
    void* args[] = { (void*)&dec_h, (void*)&dec_c, (void*)&tgt, (void*)&emb,
                     (void*)&Wih, (void*)&Whh, (void*)&bihp, (void*)&bhhp,
                     (void*)&ws, (void*)&out };
    hipLaunchCooperativeKernel(reinterpret_cast<void*>(lstm_kernel),
                               dim3(256), dim3(512), args, 131072, stream);

    // batched output projection
    proj_kernel<<<dim3(VSZ / 64, MPAD / 64), 256, 0, stream>>>(HTOP, WB, bout, out);
}

// Round 3
// 1141.640 us; speedup vs baseline: 3.6330x; 1.6543x over previous
//
#include <hip/hip_runtime.h>

// Problem constants
#define VSZ   32000
#define HSZ   512
#define LSZ   4
#define BSZ   32
#define TSZ   51            // MAX_LEN + 1
#define OUT_LOGITS 52224000 // B*T*V
#define MPAD  1664          // T*B=1632 padded to 26*64

// ws layout (float offsets)
// XH: ping-pong x|h state, [2][L][K/4=256][32 b][4] floats (k<512 = x, k>=512 = h)
#define WS_XH    0          // 262144 floats
#define WS_HTOP  262144     // bf16 [1664][512] = 851968 ushorts = 425984 float-slots
#define WS_WB    688128     // bf16 [32000][512] = 8192000 float-slots
#define WS_CNT   8880128    // u32 counters: [4][64] stage counters + [256] init

typedef __attribute__((ext_vector_type(8))) short bf16x8;
typedef __attribute__((ext_vector_type(4))) float f32x4;

static __device__ __forceinline__ unsigned short f2bf(float f) {
    unsigned int u = __float_as_uint(f);
    unsigned int r = (u + 0x7FFFu + ((u >> 16) & 1u)) >> 16;   // RNE
    return (unsigned short)r;
}

// fp32 -> (hi, lo) bf16 pair via truncation split; packs two scalars into one u32
// (element0 in low16). W ~ Whi + Wlo captures ~17 mantissa bits.
static __device__ __forceinline__ void split2(float f0, float f1,
                                              unsigned int& hi, unsigned int& lo) {
    unsigned int u0 = __float_as_uint(f0), u1 = __float_as_uint(f1);
    unsigned int h0 = u0 & 0xffff0000u, h1 = u1 & 0xffff0000u;
    hi = (u0 >> 16) | h1;
    float d0 = f0 - __uint_as_float(h0);
    float d1 = f1 - __uint_as_float(h1);
    lo = (__float_as_uint(d0) >> 16) | (__float_as_uint(d1) & 0xffff0000u);
}

// agent-scope (device-coherent) state store
static __device__ __forceinline__ void st_xh(float* p, float v) {
    __hip_atomic_store(p, v, __ATOMIC_RELAXED, __HIP_MEMORY_SCOPE_AGENT);
}
static __device__ __forceinline__ unsigned int ld_cnt(unsigned int* p) {
    return __hip_atomic_load(p, __ATOMIC_RELAXED, __HIP_MEMORY_SCOPE_AGENT);
}

// ---------------- Kernel C: W_out fp32 -> bf16 ----------------
__global__ __launch_bounds__(256) void convw_kernel(const float* __restrict__ W,
                                                    unsigned short* __restrict__ WB) {
    const int n4 = VSZ * HSZ / 4;  // 4,096,000 float4s
    for (int i = blockIdx.x * 256 + threadIdx.x; i < n4; i += gridDim.x * 256) {
        float4 f = ((const float4*)W)[i];
        ushort4 o;
        o.x = f2bf(f.x); o.y = f2bf(f.y); o.z = f2bf(f.z); o.w = f2bf(f.w);
        ((ushort4*)WB)[i] = o;
    }
}

// ---------------- Kernel A: MFMA point-to-point pipelined LSTM ----------------
// 256 blocks x 512 threads (8 waves), cooperative launch for co-residency ONLY.
// Block = (layer l = blockIdx>>6, j-tile jt = blockIdx&63): computes the
// 32-row (8 j x 4 gate) x 32-b gate tile per stage via bf16 MFMA, 3-pass hi/lo:
//   gates = Whi*Xhi + Wlo*Xhi + Whi*Xlo   (fp32 accumulate; err ~2e-5)
// Wave w: m-tile (w>>1)&1, n-tile w&1, K-half w>>2 (0: x-half/W_ih, 1: h/W_hh).
// Weights live as per-lane A-fragments in VGPRs (preloaded once, 128 VGPR);
// X is read fp32 from XH (unchanged layout/protocol) and split on the fly.
// Wave pairs (w, w+4) reduce partial accs through 4 KB LDS; waves 0-3 own the
// cell state: lane (q=lane>>4, c=lane&15) -> j = jt*8 + mt*4 + q, b = nt*16 + c,
// 4 gates in acc regs 0..3 (D-layout: row = q*4+reg = jloc*4+gate, col = b).
__global__ __launch_bounds__(512, 2) void lstm_kernel(
    const float* __restrict__ dec_h, const float* __restrict__ dec_c,
    const int* __restrict__ target, const float* __restrict__ emb,
    const float* __restrict__ Wih, const float* __restrict__ Whh,
    const float* __restrict__ bih, const float* __restrict__ bhh,
    float* __restrict__ ws, float* __restrict__ out)
{
    __shared__ f32x4 red[4][64];   // cross-wave K-reduce buffer (4 KB)

    float* XH = ws + WS_XH;                       // [2][4][256][32][4]
    unsigned short* HTOP = (unsigned short*)(ws + WS_HTOP);
    unsigned int* cnt = (unsigned int*)(ws + WS_CNT);   // [4][64] + [256]=init

    const int tid  = threadIdx.x;
    const int lane = tid & 63;
    const int w    = tid >> 6;           // wave 0..7
    const int mt   = (w >> 1) & 1;       // m-tile (rows 0-15 / 16-31)
    const int nt   = w & 1;              // n-tile (b 0-15 / 16-31)
    const int ks   = w >> 2;             // K-half: 0 = x (W_ih), 1 = h (W_hh)
    const int mi   = lane & 15;
    const int kg   = lane >> 4;          // k-group within fragment
    const int l    = blockIdx.x >> 6;    // 0..3
    const int jt   = blockIdx.x & 63;    // 0..63

    // ---- cell ownership (meaningful for waves 0..3) ----
    const int jc = jt * 8 + mt * 4 + kg;   // this lane's j (q == kg == lane>>4)
    const int bc = nt * 16 + mi;           // this lane's b (also B-frag n index)

    const int rjc = l * 2048 + jc;
    const float bias0 = bih[rjc]        + bhh[rjc];
    const float bias1 = bih[rjc + 512]  + bhh[rjc + 512];
    const float bias2 = bih[rjc + 1024] + bhh[rjc + 1024];
    const float bias3 = bih[rjc + 1536] + bhh[rjc + 1536];

    float c_reg = dec_c[(l * 32 + bc) * 512 + jc];

    // ---- one-time: preload A-fragments (weights) into VGPRs, hi/lo bf16 ----
    // A-frag layout: lane holds A[m = lane&15][k = kg*8 .. +8); row m within
    // tile mt maps to (gate = m&3, jloc = mt*4 + (m>>2)).
    bf16x8 wa_hi[16], wa_lo[16];
    {
        const int g_a   = mi & 3;
        const int jl_a  = mt * 4 + (mi >> 2);
        const int row_a = l * 2048 + g_a * 512 + jt * 8 + jl_a;
        const float* wrow = (ks ? Whh : Wih) + (size_t)row_a * 512;
        #pragma unroll
        for (int kk = 0; kk < 16; ++kk) {
            float4 v0 = *(const float4*)(wrow + kk * 32 + kg * 8);
            float4 v1 = *(const float4*)(wrow + kk * 32 + kg * 8 + 4);
            union { unsigned int u[4]; bf16x8 v; } H, L;
            split2(v0.x, v0.y, H.u[0], L.u[0]);
            split2(v0.z, v0.w, H.u[1], L.u[1]);
            split2(v1.x, v1.y, H.u[2], L.u[2]);
            split2(v1.z, v1.w, H.u[3], L.u[3]);
            wa_hi[kk] = H.v; wa_lo[kk] = L.v;
        }
    }

    // ---- init: XH[1][0][x] = emb[SOS], XH[(l+1)&1][l][h] = dec_h ----
    {
        const int gid = blockIdx.x * 512 + tid;   // 0..131071
        if (gid < 16384) {
            int k = gid >> 5, bb = gid & 31;
            st_xh(&XH[131072 + (k >> 2) * 128 + bb * 4 + (k & 3)], emb[k]);  // SOS == 0
        }
        if (gid < 65536) {
            int l2 = gid >> 14;
            int rem = gid & 16383;
            int j2 = rem >> 5, b2 = rem & 31;
            st_xh(&XH[((l2 + 1) & 1) * 131072 + l2 * 32768 +
                      (128 + (j2 >> 2)) * 128 + b2 * 4 + (j2 & 3)],
                  dec_h[(l2 * 32 + b2) * 512 + j2]);
        }
    }
    // init barrier
    __syncthreads();
    if (tid == 0) {
        __builtin_amdgcn_fence(__ATOMIC_RELEASE, "agent");
        __hip_atomic_fetch_add(&cnt[256], 1u, __ATOMIC_RELAXED, __HIP_MEMORY_SCOPE_AGENT);
        while (ld_cnt(&cnt[256]) < 256u) { __builtin_amdgcn_s_sleep(1); }
        __builtin_amdgcn_fence(__ATOMIC_ACQUIRE, "agent");
    }
    __syncthreads();

    for (int s = 0; s < 54; ++s) {
        const int pp = (s + 1) & 1;   // read parity
        const int pw = s & 1;         // write parity
        const int t  = s - l;

        // ---- WAIT: point-to-point dependency check ----
        if (s > 0 && tid == 0) {
            while (ld_cnt(&cnt[l * 64 + s - 1]) < 64u) {}
            if (l > 0) while (ld_cnt(&cnt[(l - 1) * 64 + s - 1]) < 64u) {}
            if (l < 3) while (ld_cnt(&cnt[(l + 1) * 64 + s - 1]) < 64u) {}
            __builtin_amdgcn_fence(__ATOMIC_ACQUIRE, "agent");
        }
        __syncthreads();

        // pre-pass: layer-0 blocks build layer-0 x (token t_next = s+1)
        if (l == 0 && s < 50 && tid < 256) {
            int e = jt * 256 + tid;               // 0..16383 across 64 l==0 blocks
            int k = e >> 5, bb = e & 31;
            int tok = target[bb * TSZ + s];
            st_xh(&XH[pw * 131072 + (k >> 2) * 128 + bb * 4 + (k & 3)],
                  emb[tok * 512 + k]);
        }

        if (t >= 0 && t <= 50) {
            // B-frag source: lane needs X[b = bc][k = ks*512 + kk*32 + kg*8 ..+8)
            // XH float4 index within slab: (k>>2)*32 + b
            const f32x4* xb4 = (const f32x4*)(XH + pp * 131072 + l * 32768)
                               + ks * 4096 + kg * 64 + bc;

            f32x4 acc_a = {0.f, 0.f, 0.f, 0.f};   // Whi*Xhi chain
            f32x4 acc_b = {0.f, 0.f, 0.f, 0.f};   // Wlo*Xhi + Whi*Xlo chain
            #pragma unroll
            for (int kk = 0; kk < 16; ++kk) {
                f32x4 x0 = xb4[kk * 256];
                f32x4 x1 = xb4[kk * 256 + 32];
                union { unsigned int u[4]; bf16x8 v; } XHI, XLO;
                split2(x0.x, x0.y, XHI.u[0], XLO.u[0]);
                split2(x0.z, x0.w, XHI.u[1], XLO.u[1]);
                split2(x1.x, x1.y, XHI.u[2], XLO.u[2]);
                split2(x1.z, x1.w, XHI.u[3], XLO.u[3]);
                acc_a = __builtin_amdgcn_mfma_f32_16x16x32_bf16(wa_hi[kk], XHI.v, acc_a, 0, 0, 0);
                acc_b = __builtin_amdgcn_mfma_f32_16x16x32_bf16(wa_lo[kk], XHI.v, acc_b, 0, 0, 0);
                acc_b = __builtin_amdgcn_mfma_f32_16x16x32_bf16(wa_hi[kk], XLO.v, acc_b, 0, 0, 0);
            }
            f32x4 acc = acc_a + acc_b;

            // cross-wave K-reduce: (w, w+4) share the same (mt, nt)
            __syncthreads();
            if (w >= 4) red[w - 4][lane] = acc;
            __syncthreads();
            if (w < 4) {
                f32x4 rp = red[w][lane];
                float pi = acc[0] + rp[0] + bias0;
                float pf = acc[1] + rp[1] + bias1;
                float pg = acc[2] + rp[2] + bias2;
                float po = acc[3] + rp[3] + bias3;
                float ig = 1.f / (1.f + expf(-pi));
                float fg = 1.f / (1.f + expf(-pf));
                float gg = tanhf(pg);
                float og = 1.f / (1.f + expf(-po));
                float cn = fg * c_reg + ig * gg;
                float hn = og * tanhf(cn);                  // pre-clamp h
                c_reg     = fminf(fmaxf(cn, -50.f), 50.f);
                float hcl = fminf(fmaxf(hn, -50.f), 50.f);

                // recurrent h input for own layer at t+1 (clipped)
                st_xh(&XH[pw * 131072 + l * 32768 + (128 + (jc >> 2)) * 128 + bc * 4 + (jc & 3)], hcl);
                if (l < 3)
                    st_xh(&XH[pw * 131072 + (l + 1) * 32768 + (jc >> 2) * 128 + bc * 4 + (jc & 3)], hn);
                if (l == 3)
                    HTOP[((t * 32 + bc) << 9) + jc] = f2bf(hn);   // pre-clamp top h
                if (t == 50)
                    out[OUT_LOGITS + ((l * 32 + bc) << 9) + jc] = hcl;   // h_fin
            }
        }

        // ---- ARRIVE ----
        __syncthreads();
        if (tid == 0) {
            __builtin_amdgcn_fence(__ATOMIC_RELEASE, "agent");
            __hip_atomic_fetch_add(&cnt[l * 64 + s], 1u, __ATOMIC_RELAXED,
                                   __HIP_MEMORY_SCOPE_AGENT);
        }
    }
}

// ---------------- Kernel B: bf16 MFMA projection (gemm_bt) ----------------
// C[m, v] = sum_k HTOP[m,k] * WB[v,k] + b_out[v];  m = t*32 + b  ->  out[(b*51+t)*V + v]
__global__ __launch_bounds__(256) void proj_kernel(
    const unsigned short* __restrict__ A, const unsigned short* __restrict__ Bm,
    const float* __restrict__ bout, float* __restrict__ out)
{
    __shared__ unsigned short As[64 * 40];
    __shared__ unsigned short Bs[64 * 40];
    const int tid = threadIdx.x;
    const int bn = blockIdx.x;   // 0..499
    const int bm = blockIdx.y;   // 0..25
    const int w = tid >> 6, lane = tid & 63;
    const int lr = lane & 15, lq = lane >> 4;

    f32x4 acc0 = {0.f, 0.f, 0.f, 0.f};
    f32x4 acc1 = {0.f, 0.f, 0.f, 0.f};
    f32x4 acc2 = {0.f, 0.f, 0.f, 0.f};
    f32x4 acc3 = {0.f, 0.f, 0.f, 0.f};

    const int r = tid >> 2, c8 = (tid & 3) * 8;
    const unsigned short* Ag = A + (bm * 64 + r) * HSZ + c8;
    const unsigned short* Bg = Bm + (size_t)(bn * 64 + r) * HSZ + c8;

    for (int kt = 0; kt < 16; ++kt) {
        *(uint4*)&As[r * 40 + c8] = *(const uint4*)(Ag + kt * 32);
        *(uint4*)&Bs[r * 40 + c8] = *(const uint4*)(Bg + kt * 32);
        __syncthreads();
        bf16x8 af = *(const bf16x8*)&As[(w * 16 + lr) * 40 + lq * 8];
        bf16x8 b0 = *(const bf16x8*)&Bs[(0 * 16 + lr) * 40 + lq * 8];
        bf16x8 b1 = *(const bf16x8*)&Bs[(1 * 16 + lr) * 40 + lq * 8];
        bf16x8 b2 = *(const bf16x8*)&Bs[(2 * 16 + lr) * 40 + lq * 8];
        bf16x8 b3 = *(const bf16x8*)&Bs[(3 * 16 + lr) * 40 + lq * 8];
        acc0 = __builtin_amdgcn_mfma_f32_16x16x32_bf16(af, b0, acc0, 0, 0, 0);
        acc1 = __builtin_amdgcn_mfma_f32_16x16x32_bf16(af, b1, acc1, 0, 0, 0);
        acc2 = __builtin_amdgcn_mfma_f32_16x16x32_bf16(af, b2, acc2, 0, 0, 0);
        acc3 = __builtin_amdgcn_mfma_f32_16x16x32_bf16(af, b3, acc3, 0, 0, 0);
        __syncthreads();
    }

    f32x4 accs[4] = {acc0, acc1, acc2, acc3};
    #pragma unroll
    for (int nt = 0; nt < 4; ++nt) {
        const int v = bn * 64 + nt * 16 + lr;
        const float bo = bout[v];
        #pragma unroll
        for (int reg = 0; reg < 4; ++reg) {
            const int m = bm * 64 + w * 16 + lq * 4 + reg;
            if (m < TSZ * BSZ) {
                const int tt = m >> 5, bb = m & 31;
                out[(size_t)(bb * TSZ + tt) * VSZ + v] = accs[nt][reg] + bo;
            }
        }
    }
}

extern "C" void kernel_launch(void* const* d_in, const int* in_sizes, int n_in,
                              void* d_out, int out_size, void* d_ws, size_t ws_size,
                              hipStream_t stream) {
    const float* dec_h = (const float*)d_in[1];
    const float* dec_c = (const float*)d_in[2];
    const int*   tgt   = (const int*)d_in[3];
    const float* emb   = (const float*)d_in[4];
    const float* Wih   = (const float*)d_in[5];
    const float* Whh   = (const float*)d_in[6];
    const float* bihp  = (const float*)d_in[7];
    const float* bhhp  = (const float*)d_in[8];
    const float* Wout  = (const float*)d_in[9];
    const float* bout  = (const float*)d_in[10];
    float* out = (float*)d_out;
    float* ws  = (float*)d_ws;

    unsigned short* HTOP = (unsigned short*)(ws + WS_HTOP);
    unsigned short* WB   = (unsigned short*)(ws + WS_WB);

    // zero the p2p sync counters (graph-capture safe)
    hipMemsetAsync(ws + WS_CNT, 0, 1040, stream);

    // W_out -> bf16 (independent of the recurrence)
    convw_kernel<<<4096, 256, 0, stream>>>(Wout, WB);

    // MFMA point-to-point pipelined LSTM (cooperative launch for co-residency)
    void* args[] = { (void*)&dec_h, (void*)&dec_c, (void*)&tgt, (void*)&emb,
                     (void*)&Wih, (void*)&Whh, (void*)&bihp, (void*)&bhhp,
                     (void*)&ws, (void*)&out };
    hipLaunchCooperativeKernel(reinterpret_cast<void*>(lstm_kernel),
                               dim3(256), dim3(512), args, 0, stream);

    // batched output projection
    proj_kernel<<<dim3(VSZ / 64, MPAD / 64), 256, 0, stream>>>(HTOP, WB, bout, out);
}